// Round 1
// 520.490 us; speedup vs baseline: 1.0246x; 1.0246x over previous
//
#include <hip/hip_runtime.h>
#include <stdint.h>

#define D 128
#define MT 64

typedef short short8 __attribute__((ext_vector_type(8)));
typedef float f32x16 __attribute__((ext_vector_type(16)));

__device__ __forceinline__ unsigned short f2bf(float f) {
    union { float f; uint32_t u; } v;
    v.f = f;
    uint32_t u = v.u;
    uint32_t r = (u + 0x7fffu + ((u >> 16) & 1u)) >> 16;  // RNE
    return (unsigned short)r;
}

// Pack W1 (384x128) / W2 (128x128) fp32 row-major -> bf16 MFMA-B fragment order:
// frag index ((kt*4 + nt)*64 + lane)*8 + j holds W[k = kt*16 + (lane>>5)*8 + j][n = nt*32 + (lane&31)]
__global__ void pack_weights_kernel(const float* __restrict__ W1,
                                    const float* __restrict__ W2,
                                    unsigned short* __restrict__ W1p,
                                    unsigned short* __restrict__ W2p) {
    int t = blockIdx.x * 256 + threadIdx.x;
    if (t < 6144) {               // W1: 24 ksteps * 4 colblocks * 64 lanes
        int kt = t >> 8, nt = (t >> 6) & 3, lane = t & 63;
        int n = nt * 32 + (lane & 31);
        int kb = kt * 16 + (lane >> 5) * 8;
        unsigned short* dst = W1p + t * 8;
        #pragma unroll
        for (int j = 0; j < 8; ++j) dst[j] = f2bf(W1[(kb + j) * D + n]);
    } else if (t < 8192) {        // W2: 8 ksteps * 4 colblocks * 64 lanes
        int u = t - 6144;
        int kt = u >> 8, nt = (u >> 6) & 3, lane = u & 63;
        int n = nt * 32 + (lane & 31);
        int kb = kt * 16 + (lane >> 5) * 8;
        unsigned short* dst = W2p + u * 8;
        #pragma unroll
        for (int j = 0; j < 8; ++j) dst[j] = f2bf(W2[(kb + j) * D + n]);
    }
}

// 64 edges per block, 512 threads = 8 waves. Wave w = (row-tile rt = w>>2, col-block cb = w&3):
// one 32x32 output tile per wave -> single f32x16 accumulator, VGPR ~55.
// X_cat staged bf16 in LDS (stride 392 = 49*16B, measured 0 bank conflicts).
// H aliases the same LDS (barrier-separated) to stay <= 50 KB -> 3 blocks/CU = 24 waves/CU (75%).
__global__ __launch_bounds__(512, 6) void edge_mlp_kernel(
    const float* __restrict__ x_node,
    const float* __restrict__ x_edge,
    const int* __restrict__ eidx,
    const unsigned short* __restrict__ W1p,
    const unsigned short* __restrict__ W2p,
    const float* __restrict__ b1,
    const float* __restrict__ b2,
    float* __restrict__ out,
    int E) {
    __shared__ unsigned short lds[MT * 392];   // 50176 B
    unsigned short* Hs = lds;                  // aliased, stride 136 (17*16B)

    const int t = threadIdx.x;
    const int r0 = blockIdx.x * MT;

    // ---- stage: gather v0|v1|x_edge, convert fp32->bf16, write LDS ----
    {
        const int lane32 = t & 31;
        const int rsub = t >> 5;               // 0..15
        #pragma unroll
        for (int rb = 0; rb < 4; ++rb) {
            int row = rb * 16 + rsub;          // 0..63
            int rg = r0 + row;
            int rgc = rg < E ? rg : E - 1;
            int e0 = eidx[2 * rgc];
            int e1 = eidx[2 * rgc + 1];
            float4 v0 = ((const float4*)(x_node + (size_t)e0 * D))[lane32];
            float4 v1 = ((const float4*)(x_node + (size_t)e1 * D))[lane32];
            float4 v2 = ((const float4*)(x_edge + (size_t)rgc * D))[lane32];
            unsigned short* base = &lds[row * 392 + lane32 * 4];
            ushort4 p;
            p.x = f2bf(v0.x); p.y = f2bf(v0.y); p.z = f2bf(v0.z); p.w = f2bf(v0.w);
            *(ushort4*)(base) = p;
            p.x = f2bf(v1.x); p.y = f2bf(v1.y); p.z = f2bf(v1.z); p.w = f2bf(v1.w);
            *(ushort4*)(base + 128) = p;
            p.x = f2bf(v2.x); p.y = f2bf(v2.y); p.z = f2bf(v2.z); p.w = f2bf(v2.w);
            *(ushort4*)(base + 256) = p;
        }
    }
    __syncthreads();

    const int w = t >> 6;                 // wave id 0..7
    const int cb = w & 3;                 // column block (32 cols)
    const int rt = w >> 2;                // row tile (32 rows)
    const int lane = t & 63;
    const int lrow = lane & 31;           // m within 32-tile / n within col block
    const int khalf = (lane >> 5) * 8;    // k-half select
    const int n = cb * 32 + lrow;
    const int rbump = (lane >> 5) * 4;
    const int arow = rt * 32 + lrow;      // A-operand row

    // ---- GEMM1: H = relu(X_cat @ W1 + b1), K = 384 ----
    f32x16 acc;
    #pragma unroll
    for (int i = 0; i < 16; ++i) acc[i] = 0.f;

    for (int kt = 0; kt < 24; ++kt) {
        short8 a = *(const short8*)&lds[arow * 392 + kt * 16 + khalf];
        short8 b = *(const short8*)(W1p + ((kt * 4 + cb) * 64 + lane) * 8);
        acc = __builtin_amdgcn_mfma_f32_32x32x16_bf16(a, b, acc, 0, 0, 0);
    }
    __syncthreads();   // everyone done reading X_cat before H overwrites it

    {
        float b1v = b1[n];
        #pragma unroll
        for (int r = 0; r < 16; ++r) {
            int rr = rt * 32 + (r & 3) + 8 * (r >> 2) + rbump;   // C-layout row
            Hs[rr * 136 + n] = f2bf(fmaxf(acc[r] + b1v, 0.f));
        }
    }
    __syncthreads();

    // ---- GEMM2: OUT = H @ W2 + b2, K = 128 ----
    f32x16 c;
    #pragma unroll
    for (int i = 0; i < 16; ++i) c[i] = 0.f;

    #pragma unroll
    for (int kt = 0; kt < 8; ++kt) {
        short8 a = *(const short8*)&Hs[arow * 136 + kt * 16 + khalf];
        short8 b = *(const short8*)(W2p + ((kt * 4 + cb) * 64 + lane) * 8);
        c = __builtin_amdgcn_mfma_f32_32x32x16_bf16(a, b, c, 0, 0, 0);
    }

    {
        float b2v = b2[n];
        #pragma unroll
        for (int r = 0; r < 16; ++r) {
            int rr = rt * 32 + (r & 3) + 8 * (r >> 2) + rbump;
            int rg = r0 + rr;
            if (rg < E) out[(size_t)rg * D + n] = c[r] + b2v;
        }
    }
}

extern "C" void kernel_launch(void* const* d_in, const int* in_sizes, int n_in,
                              void* d_out, int out_size, void* d_ws, size_t ws_size,
                              hipStream_t stream) {
    const float* x_node = (const float*)d_in[0];
    const float* x_edge = (const float*)d_in[1];
    const int*   eidx   = (const int*)d_in[2];
    const float* W1     = (const float*)d_in[3];
    const float* b1     = (const float*)d_in[4];
    const float* W2     = (const float*)d_in[5];
    const float* b2     = (const float*)d_in[6];
    float* out = (float*)d_out;

    const int E = in_sizes[1] / D;

    unsigned short* W1p = (unsigned short*)d_ws;          // 6144*8 bf16 = 96 KB
    unsigned short* W2p = W1p + 6144 * 8;                 // 2048*8 bf16 = 32 KB

    pack_weights_kernel<<<32, 256, 0, stream>>>(W1, W2, W1p, W2p);

    int nblk = (E + MT - 1) / MT;
    edge_mlp_kernel<<<nblk, 512, 0, stream>>>(x_node, x_edge, eidx, W1p, W2p, b1, b2, out, E);
}